// Round 1
// baseline (390.287 us; speedup 1.0000x reference)
//
#include <hip/hip_runtime.h>

#define HH 256
#define WW 256
#define CC 96
#define BB 8

__device__ __forceinline__ float silu_of(float z) {
    return z / (1.0f + __expf(-z));
}

__global__ __launch_bounds__(256, 4)
void trifreq_kernel(const float* __restrict__ x,
                    const float* __restrict__ w_lo,
                    const float* __restrict__ w_mf,
                    const float* __restrict__ w_hf,
                    const float* __restrict__ gamma,
                    const float* __restrict__ beta,
                    const float* __restrict__ mean,
                    const float* __restrict__ var,
                    float* __restrict__ out)
{
    // xs: input tile with halo 4: rows/cols tile-rel -4..67 -> idx +4, stride 72
    __shared__ float xs[72 * 72];
    // tmp: band/high-pass tile, coords -2..65 -> idx +2, stride 68 (ring at -2/65 is garbage, unused)
    __shared__ float tmp[68 * 68];

    const int tid = threadIdx.x;
    const int tileIdx = blockIdx.x;          // 0..15
    const int c = blockIdx.y;                // 0..95 (concat order == input channel)
    const int b = blockIdx.z;                // 0..7
    const int th = (tileIdx >> 2) * 64;      // tile origin h
    const int tw = (tileIdx & 3) * 64;       // tile origin w

    const int g = c >> 5;                    // 0=lo,1=mf,2=hf
    const int ci = c & 31;
    const int c_out = ci * 3 + g;            // channel-shuffle output index

    const float* __restrict__ xin = x + (((size_t)b * CC + c) * (size_t)HH) * (size_t)WW;

    // ---------------- stage input tile + halo(4), zero outside image ----------------
    // 72 rows x 18 float4 (all segments 16B aligned; image bounds fall on float4 edges)
    for (int idx = tid; idx < 72 * 18; idx += 256) {
        const int r  = idx / 18;
        const int c4 = idx % 18;
        const int gh = th - 4 + r;
        const int gw = tw - 4 + 4 * c4;
        float4 v = make_float4(0.f, 0.f, 0.f, 0.f);
        if (gh >= 0 && gh < HH && gw >= 0 && gw + 3 < WW) {
            v = *reinterpret_cast<const float4*>(xin + (size_t)gh * WW + gw);
        }
        *reinterpret_cast<float4*>(&xs[r * 72 + 4 * c4]) = v;
    }
    __syncthreads();

    const int qr = (tid >> 4) << 2;   // output patch base row (0..60)
    const int qc = (tid & 15) << 2;   // output patch base col (0..60)
    float acc[4][4];

    if (g == 0) {
        // ---------------- low band: direct 5x5 depthwise conv ----------------
        const float* __restrict__ wp = w_lo + ci * 25;
        float wk[25];
        #pragma unroll
        for (int t = 0; t < 25; ++t) wk[t] = wp[t];
        #pragma unroll
        for (int i = 0; i < 4; ++i)
            #pragma unroll
            for (int j = 0; j < 4; ++j) acc[i][j] = 0.f;

        #pragma unroll
        for (int rr = 0; rr < 8; ++rr) {
            // x row tile-rel = qr-2+rr -> xs idx qr+rr+2 ; col start qc-2 -> idx qc+2
            const float* row = &xs[(qr + rr + 2) * 72 + (qc + 2)];
            float v[8];
            #pragma unroll
            for (int j = 0; j < 8; ++j) v[j] = row[j];
            #pragma unroll
            for (int i = 0; i < 4; ++i) {
                const int ki = rr - i;
                if (ki >= 0 && ki < 5) {
                    #pragma unroll
                    for (int j = 0; j < 4; ++j)
                        acc[i][j] += v[j + 0] * wk[ki * 5 + 0]
                                   + v[j + 1] * wk[ki * 5 + 1]
                                   + v[j + 2] * wk[ki * 5 + 2]
                                   + v[j + 3] * wk[ki * 5 + 3]
                                   + v[j + 4] * wk[ki * 5 + 4];
                }
            }
        }
    } else {
        if (g == 1) {
            // ---------------- mid band: bandpass = avg3 - avg7 into tmp ----------------
            for (int p = tid; p < 17 * 17; p += 256) {
                const int pr = p / 17, pc = p % 17;
                const int br = pr * 4 - 2, bc = pc * 4 - 2;   // bp patch base (tile-rel)
                float v7a[4][4] = {};
                float v3a[4][4] = {};
                #pragma unroll
                for (int rr = 0; rr < 10; ++rr) {
                    int xr = br - 3 + rr + 4;          // xs row idx (clamp: only garbage ring clamps)
                    xr = max(0, min(71, xr));
                    const float* row = &xs[xr * 72];
                    float v[10];
                    #pragma unroll
                    for (int j = 0; j < 10; ++j) {
                        int xc = bc - 3 + j + 4;
                        xc = max(0, min(71, xc));
                        v[j] = row[xc];
                    }
                    float h7[4], h3[4];
                    float s = v[0] + v[1] + v[2] + v[3] + v[4] + v[5] + v[6];
                    h7[0] = s;
                    h7[1] = h7[0] + v[7] - v[0];
                    h7[2] = h7[1] + v[8] - v[1];
                    h7[3] = h7[2] + v[9] - v[2];
                    #pragma unroll
                    for (int j = 0; j < 4; ++j) h3[j] = v[j + 2] + v[j + 3] + v[j + 4];
                    #pragma unroll
                    for (int k = 0; k < 4; ++k) {
                        if (rr >= k && rr <= k + 6) {         // pool7 rows: rr = k..k+6
                            #pragma unroll
                            for (int j = 0; j < 4; ++j) v7a[k][j] += h7[j];
                        }
                        if (rr >= k + 2 && rr <= k + 4) {     // pool3 rows: rr = k+2..k+4
                            #pragma unroll
                            for (int j = 0; j < 4; ++j) v3a[k][j] += h3[j];
                        }
                    }
                }
                // count_include_pad=False reciprocal counts (per row/col, hoisted)
                float r3h[4], r7h[4], r3w[4], r7w[4];
                #pragma unroll
                for (int i = 0; i < 4; ++i) {
                    const int hh = th + br + i;
                    const int a3 = min(hh + 1, HH - 1) - max(hh - 1, 0) + 1;
                    const int a7 = min(hh + 3, HH - 1) - max(hh - 3, 0) + 1;
                    r3h[i] = 1.0f / (float)a3;
                    r7h[i] = 1.0f / (float)a7;
                }
                #pragma unroll
                for (int j = 0; j < 4; ++j) {
                    const int ww = tw + bc + j;
                    const int a3 = min(ww + 1, WW - 1) - max(ww - 1, 0) + 1;
                    const int a7 = min(ww + 3, WW - 1) - max(ww - 3, 0) + 1;
                    r3w[j] = 1.0f / (float)a3;
                    r7w[j] = 1.0f / (float)a7;
                }
                #pragma unroll
                for (int i = 0; i < 4; ++i) {
                    const int hh = th + br + i;
                    #pragma unroll
                    for (int j = 0; j < 4; ++j) {
                        const int ww = tw + bc + j;
                        float bp = 0.f;
                        if (hh >= 0 && hh < HH && ww >= 0 && ww < WW)
                            bp = v3a[i][j] * (r3h[i] * r3w[j]) - v7a[i][j] * (r7h[i] * r7w[j]);
                        tmp[(br + i + 2) * 68 + (bc + j + 2)] = bp;
                    }
                }
            }
        } else {
            // ---------------- high band: highpass = x - avg3 into tmp ----------------
            for (int p = tid; p < 17 * 17; p += 256) {
                const int pr = p / 17, pc = p % 17;
                const int br = pr * 4 - 2, bc = pc * 4 - 2;
                float v3a[4][4] = {};
                float cen[4][4];
                #pragma unroll
                for (int rr = 0; rr < 6; ++rr) {
                    const int xr = br - 1 + rr + 4;   // in [1,70] always — no clamp needed
                    const float* row = &xs[xr * 72];
                    float v[6];
                    #pragma unroll
                    for (int j = 0; j < 6; ++j) v[j] = row[bc - 1 + j + 4];
                    float h3[4];
                    #pragma unroll
                    for (int j = 0; j < 4; ++j) h3[j] = v[j] + v[j + 1] + v[j + 2];
                    if (rr >= 1 && rr <= 4) {
                        #pragma unroll
                        for (int j = 0; j < 4; ++j) cen[rr - 1][j] = v[j + 1];
                    }
                    #pragma unroll
                    for (int k = 0; k < 4; ++k) {
                        if (rr >= k && rr <= k + 2) {
                            #pragma unroll
                            for (int j = 0; j < 4; ++j) v3a[k][j] += h3[j];
                        }
                    }
                }
                float r3h[4], r3w[4];
                #pragma unroll
                for (int i = 0; i < 4; ++i) {
                    const int hh = th + br + i;
                    const int a3 = min(hh + 1, HH - 1) - max(hh - 1, 0) + 1;
                    r3h[i] = 1.0f / (float)a3;
                }
                #pragma unroll
                for (int j = 0; j < 4; ++j) {
                    const int ww = tw + bc + j;
                    const int a3 = min(ww + 1, WW - 1) - max(ww - 1, 0) + 1;
                    r3w[j] = 1.0f / (float)a3;
                }
                #pragma unroll
                for (int i = 0; i < 4; ++i) {
                    const int hh = th + br + i;
                    #pragma unroll
                    for (int j = 0; j < 4; ++j) {
                        const int ww = tw + bc + j;
                        float hp = 0.f;
                        if (hh >= 0 && hh < HH && ww >= 0 && ww < WW)
                            hp = cen[i][j] - v3a[i][j] * (r3h[i] * r3w[j]);
                        tmp[(br + i + 2) * 68 + (bc + j + 2)] = hp;
                    }
                }
            }
        }
        __syncthreads();

        // ---------------- 3x3 depthwise conv over tmp ----------------
        const float* __restrict__ wp = ((g == 1) ? w_mf : w_hf) + ci * 9;
        float wk[9];
        #pragma unroll
        for (int t = 0; t < 9; ++t) wk[t] = wp[t];
        #pragma unroll
        for (int i = 0; i < 4; ++i)
            #pragma unroll
            for (int j = 0; j < 4; ++j) acc[i][j] = 0.f;

        #pragma unroll
        for (int rr = 0; rr < 6; ++rr) {
            // t row tile-rel = qr-1+rr -> idx qr+rr+1 ; col start qc-1 -> idx qc+1
            const float* row = &tmp[(qr + rr + 1) * 68 + (qc + 1)];
            float v[6];
            #pragma unroll
            for (int j = 0; j < 6; ++j) v[j] = row[j];
            #pragma unroll
            for (int i = 0; i < 4; ++i) {
                const int ki = rr - i;
                if (ki >= 0 && ki < 3) {
                    #pragma unroll
                    for (int j = 0; j < 4; ++j)
                        acc[i][j] += v[j + 0] * wk[ki * 3 + 0]
                                   + v[j + 1] * wk[ki * 3 + 1]
                                   + v[j + 2] * wk[ki * 3 + 2];
                }
            }
        }
    }

    // ---------------- BN + SiLU + store (channel-shuffled) ----------------
    const float bninv  = gamma[c_out] * rsqrtf(var[c_out] + 1e-5f);
    const float bnbias = beta[c_out] - mean[c_out] * bninv;
    float* __restrict__ op = out + (((size_t)b * CC + c_out) * (size_t)HH + (th + qr)) * (size_t)WW + (tw + qc);
    #pragma unroll
    for (int i = 0; i < 4; ++i) {
        float4 o;
        const float z0 = acc[i][0] * bninv + bnbias;
        const float z1 = acc[i][1] * bninv + bnbias;
        const float z2 = acc[i][2] * bninv + bnbias;
        const float z3 = acc[i][3] * bninv + bnbias;
        o.x = silu_of(z0);
        o.y = silu_of(z1);
        o.z = silu_of(z2);
        o.w = silu_of(z3);
        *reinterpret_cast<float4*>(op + (size_t)i * WW) = o;
    }
}

extern "C" void kernel_launch(void* const* d_in, const int* in_sizes, int n_in,
                              void* d_out, int out_size, void* d_ws, size_t ws_size,
                              hipStream_t stream) {
    const float* x     = (const float*)d_in[0];
    const float* w_lo  = (const float*)d_in[1];
    const float* w_mf  = (const float*)d_in[2];
    const float* w_hf  = (const float*)d_in[3];
    const float* gam   = (const float*)d_in[4];
    const float* bet   = (const float*)d_in[5];
    const float* mea   = (const float*)d_in[6];
    const float* va    = (const float*)d_in[7];
    float* out = (float*)d_out;

    dim3 grid(16, CC, BB);
    dim3 block(256);
    hipLaunchKernelGGL(trifreq_kernel, grid, block, 0, stream,
                       x, w_lo, w_mf, w_hf, gam, bet, mea, va, out);
}